// Round 1
// baseline (57.187 us; speedup 1.0000x reference)
//
#include <hip/hip_runtime.h>

#define TSTEPS 32
#define HW 65536   // 256*256
#define NB 32      // batch
#define N_ELEM (NB * HW)        // 2,097,152
#define N4 (N_ELEM / 4)         // 524,288

// Order-preserving float<->uint key (works for all floats incl. negatives)
__device__ __forceinline__ unsigned int f2key(float f) {
    unsigned int u = __float_as_uint(f);
    return (u & 0x80000000u) ? ~u : (u | 0x80000000u);
}
__device__ __forceinline__ float key2f(unsigned int k) {
    unsigned int u = (k & 0x80000000u) ? (k & 0x7fffffffu) : ~k;
    return __uint_as_float(u);
}

__global__ void lc_init_ws(unsigned int* ws) {
    if (threadIdx.x == 0) {
        ws[0] = 0xFFFFFFFFu;  // running MIN key (init = +inf key)
        ws[1] = 0x00000000u;  // running MAX key (init = -inf key)
    }
}

__global__ void lc_minmax(const float4* __restrict__ in, unsigned int* __restrict__ ws) {
    __shared__ unsigned int smin[4], smax[4];
    unsigned int kmin = 0xFFFFFFFFu, kmax = 0u;
    int stride = gridDim.x * blockDim.x;
    for (int i = blockIdx.x * blockDim.x + threadIdx.x; i < N4; i += stride) {
        float4 v = in[i];
        unsigned int k;
        k = f2key(v.x); kmin = min(kmin, k); kmax = max(kmax, k);
        k = f2key(v.y); kmin = min(kmin, k); kmax = max(kmax, k);
        k = f2key(v.z); kmin = min(kmin, k); kmax = max(kmax, k);
        k = f2key(v.w); kmin = min(kmin, k); kmax = max(kmax, k);
    }
    // wave64 butterfly reduce
    #pragma unroll
    for (int off = 32; off >= 1; off >>= 1) {
        kmin = min(kmin, (unsigned int)__shfl_xor((int)kmin, off, 64));
        kmax = max(kmax, (unsigned int)__shfl_xor((int)kmax, off, 64));
    }
    int wave = threadIdx.x >> 6;
    if ((threadIdx.x & 63) == 0) { smin[wave] = kmin; smax[wave] = kmax; }
    __syncthreads();
    if (threadIdx.x == 0) {
        #pragma unroll
        for (int w = 1; w < 4; ++w) {
            kmin = min(kmin, smin[w]);
            kmax = max(kmax, smax[w]);
        }
        atomicMin(&ws[0], kmin);
        atomicMax(&ws[1], kmax);
    }
}

__device__ __forceinline__ int spike_t(float x, float mn, float denom, bool valid) {
    // EXACT reference op order: n=(x-mn)/denom ; lat=(1-n)*1.0 ; t=trunc(lat*31)
    float n   = valid ? ((x - mn) / denom) : 0.5f;
    float lat = 1.0f - n;                 // * MAX_LATENCY(=1.0) is exact
    int   t   = (int)(lat * 31.0f);       // lat >= 0 so trunc == floor
    t = t < 0 ? 0 : t;
    t = t > (TSTEPS - 1) ? (TSTEPS - 1) : t;
    return t;
}

__global__ void lc_spike(const float4* __restrict__ in, float* __restrict__ out,
                         const unsigned int* __restrict__ ws) {
    float mn = key2f(ws[0]);
    float mx = key2f(ws[1]);
    bool  valid = (mx > mn);
    float denom = fmaxf(mx - mn, 1e-12f);

    int idx = blockIdx.x * blockDim.x + threadIdx.x;   // 0 .. N4-1
    if (idx >= N4) return;
    int b   = idx >> 14;          // idx / (HW/4)
    int rem = idx & 16383;        // idx % (HW/4)

    float4 v = in[idx];
    int t0 = spike_t(v.x, mn, denom, valid);
    int t1 = spike_t(v.y, mn, denom, valid);
    int t2 = spike_t(v.z, mn, denom, valid);
    int t3 = spike_t(v.w, mn, denom, valid);

    float* base = out + (size_t)b * TSTEPS * HW + (size_t)rem * 4;
    #pragma unroll
    for (int tt = 0; tt < TSTEPS; ++tt) {
        float4 o;
        o.x = (tt == t0) ? 1.0f : 0.0f;
        o.y = (tt == t1) ? 1.0f : 0.0f;
        o.z = (tt == t2) ? 1.0f : 0.0f;
        o.w = (tt == t3) ? 1.0f : 0.0f;
        *reinterpret_cast<float4*>(base + (size_t)tt * HW) = o;
    }
}

extern "C" void kernel_launch(void* const* d_in, const int* in_sizes, int n_in,
                              void* d_out, int out_size, void* d_ws, size_t ws_size,
                              hipStream_t stream) {
    const float4*  in = (const float4*)d_in[0];
    float*        out = (float*)d_out;
    unsigned int*  ws = (unsigned int*)d_ws;

    lc_init_ws<<<1, 64, 0, stream>>>(ws);
    lc_minmax<<<256, 256, 0, stream>>>(in, ws);
    lc_spike<<<(N4 + 255) / 256, 256, 0, stream>>>(in, out, ws);
}